// Round 1
// baseline (167.237 us; speedup 1.0000x reference)
//
#include <hip/hip_runtime.h>
#include <hip/hip_bf16.h>

#define S_DIM 2048
#define G_DIM 8
#define D_DIM 128
#define N_ROWS (S_DIM * G_DIM)   // 16384
#define SCALE 30.0f

typedef __attribute__((ext_vector_type(8))) short bf16x8;
typedef __attribute__((ext_vector_type(4))) float f32x4;

__device__ __forceinline__ float wave_allreduce_sum(float v) {
    #pragma unroll
    for (int m = 32; m >= 1; m >>= 1) v += __shfl_xor(v, m, 64);
    return v;
}

// ---------------------------------------------------------------------------
// Kernel A: normalize rows, centroids, exclusive-centroid cosine (all fp32),
// emit bf16 xn and bf16 cent_n for the MFMA stage.
// One block per speaker s; 8 waves = 8 utterances; lane handles dims l, l+64.
// ---------------------------------------------------------------------------
__global__ __launch_bounds__(512) void prep_kernel(
    const float* __restrict__ x,          // [S][G][D]
    __hip_bfloat16* __restrict__ xnb,     // [S*G][D]
    __hip_bfloat16* __restrict__ centb,   // [S][D]
    float* __restrict__ cosexc)           // [S*G]
{
    __shared__ float xs[G_DIM][D_DIM];
    __shared__ float csum[D_DIM];

    const int s    = blockIdx.x;
    const int g    = threadIdx.x >> 6;
    const int lane = threadIdx.x & 63;
    const int d0 = lane, d1 = lane + 64;

    const float* xr = x + (s * G_DIM + g) * D_DIM;
    float a0 = xr[d0], a1 = xr[d1];

    // row L2 normalize (clip 1e-12)
    float ss  = wave_allreduce_sum(a0 * a0 + a1 * a1);
    float inv = 1.0f / fmaxf(sqrtf(ss), 1e-12f);
    float x0 = a0 * inv, x1 = a1 * inv;

    xs[g][d0] = x0;
    xs[g][d1] = x1;
    __hip_bfloat16* xw = xnb + (s * G_DIM + g) * D_DIM;
    xw[d0] = __float2bfloat16(x0);
    xw[d1] = __float2bfloat16(x1);
    __syncthreads();

    // column sums over g
    if (threadIdx.x < D_DIM) {
        float c = 0.0f;
        #pragma unroll
        for (int gg = 0; gg < G_DIM; ++gg) c += xs[gg][threadIdx.x];
        csum[threadIdx.x] = c;
    }
    __syncthreads();

    // exclusive centroid: (sum - xn)/(G-1), normalize (clip 1e-8), cosine w/ xn
    float e0 = (csum[d0] - x0) * (1.0f / (G_DIM - 1));
    float e1 = (csum[d1] - x1) * (1.0f / (G_DIM - 1));
    float ess = wave_allreduce_sum(e0 * e0 + e1 * e1);
    float ed  = fmaxf(sqrtf(ess), 1e-8f);
    float dot = wave_allreduce_sum(x0 * e0 + x1 * e1);
    if (lane == 0) cosexc[s * G_DIM + g] = dot / ed;

    // centroid: cent = csum/8, cent_n = cent / clip(||cent||, 1e-8)
    if (g == 0) {
        float c0 = csum[d0], c1 = csum[d1];
        float css  = wave_allreduce_sum(c0 * c0 + c1 * c1);
        float cnrm = sqrtf(css) * (1.0f / G_DIM);          // ||cent||
        float scl  = (1.0f / G_DIM) / fmaxf(cnrm, 1e-8f);
        centb[s * D_DIM + d0] = __float2bfloat16(c0 * scl);
        centb[s * D_DIM + d1] = __float2bfloat16(c1 * scl);
    }
}

// ---------------------------------------------------------------------------
// Kernel B: scores via MFMA bf16 (fp32 acc) fused with softmax-denominator.
// Each wave owns 16 rows; loops t over 2048 in chunks of 16.
// A-frag layout (16x16x32): A[m=lane&15][k=(lane>>4)*8 + j], j=0..7
// C/D layout: col(n) = lane&15, row(m) = (lane>>4)*4 + reg   [m89-verified]
// logsumexp uses fixed offset 30 (all logits <= 30, >= 1e-6): no max pass.
// ---------------------------------------------------------------------------
__global__ __launch_bounds__(256) void score_kernel(
    const __hip_bfloat16* __restrict__ xnb,    // [N_ROWS][D]
    const __hip_bfloat16* __restrict__ centb,  // [S][D]
    const float* __restrict__ cosexc,          // [N_ROWS]
    float* __restrict__ row_loss)              // [N_ROWS]
{
    const int wave = threadIdx.x >> 6;
    const int lane = threadIdx.x & 63;
    const int row0 = blockIdx.x * 64 + wave * 16;
    const int nIdx = lane & 15;   // A row-within-tile AND C col(t) index
    const int quad = lane >> 4;

    // A fragments resident: 16 rows x 128 k
    const short* xsrc = (const short*)xnb;
    bf16x8 afrag[4];
    const int abase = (row0 + nIdx) * D_DIM + quad * 8;
    #pragma unroll
    for (int kc = 0; kc < 4; ++kc)
        afrag[kc] = *(const bf16x8*)(xsrc + abase + kc * 32);

    float sumexp[4] = {0.0f, 0.0f, 0.0f, 0.0f};
    float llab[4]   = {0.0f, 0.0f, 0.0f, 0.0f};

    const short* csrc = (const short*)centb;
    for (int t0 = 0; t0 < S_DIM; t0 += 16) {
        f32x4 acc = {0.0f, 0.0f, 0.0f, 0.0f};
        const int bbase = (t0 + nIdx) * D_DIM + quad * 8;
        #pragma unroll
        for (int kc = 0; kc < 4; ++kc) {
            bf16x8 bfrag = *(const bf16x8*)(csrc + bbase + kc * 32);
            acc = __builtin_amdgcn_mfma_f32_16x16x32_bf16(afrag[kc], bfrag, acc, 0, 0, 0);
        }
        const int t = t0 + nIdx;
        #pragma unroll
        for (int r = 0; r < 4; ++r) {
            const int grow = row0 + quad * 4 + r;
            float l = fmaxf(SCALE * acc[r], 1e-6f);
            if (t == (grow >> 3)) {              // diagonal: own-speaker entry
                l = fmaxf(SCALE * cosexc[grow], 1e-6f);
                llab[r] = l;                      // label logit (exact fp32)
            }
            sumexp[r] += __expf(l - SCALE);
        }
    }

    // reduce across the 16 lanes sharing a quad (they cover t mod 16)
    #pragma unroll
    for (int r = 0; r < 4; ++r) {
        #pragma unroll
        for (int msk = 1; msk <= 8; msk <<= 1) {
            sumexp[r] += __shfl_xor(sumexp[r], msk, 64);
            llab[r]   += __shfl_xor(llab[r], msk, 64);
        }
    }
    if (nIdx == 0) {
        #pragma unroll
        for (int r = 0; r < 4; ++r) {
            const int grow = row0 + quad * 4 + r;
            row_loss[grow] = SCALE + logf(sumexp[r]) - llab[r];
        }
    }
}

// ---------------------------------------------------------------------------
// Kernel C: mean of row losses -> scalar
// ---------------------------------------------------------------------------
__global__ __launch_bounds__(256) void reduce_kernel(
    const float* __restrict__ row_loss, float* __restrict__ out)
{
    __shared__ float red[4];
    float acc = 0.0f;
    for (int i = threadIdx.x; i < N_ROWS; i += 256) acc += row_loss[i];
    acc = wave_allreduce_sum(acc);
    const int wave = threadIdx.x >> 6;
    if ((threadIdx.x & 63) == 0) red[wave] = acc;
    __syncthreads();
    if (threadIdx.x == 0)
        out[0] = (red[0] + red[1] + red[2] + red[3]) * (1.0f / N_ROWS);
}

extern "C" void kernel_launch(void* const* d_in, const int* in_sizes, int n_in,
                              void* d_out, int out_size, void* d_ws, size_t ws_size,
                              hipStream_t stream) {
    const float* x = (const float*)d_in[0];
    char* ws = (char*)d_ws;

    __hip_bfloat16* xnb   = (__hip_bfloat16*)ws;                         // 4 MB
    __hip_bfloat16* centb = (__hip_bfloat16*)(ws + (size_t)N_ROWS * D_DIM * 2);  // 0.5 MB
    float* cosexc   = (float*)(ws + (size_t)N_ROWS * D_DIM * 2 + (size_t)S_DIM * D_DIM * 2);
    float* row_loss = cosexc + N_ROWS;
    float* out = (float*)d_out;

    prep_kernel<<<S_DIM, 512, 0, stream>>>(x, xnb, centb, cosexc);
    score_kernel<<<N_ROWS / 64, 256, 0, stream>>>(xnb, centb, cosexc, row_loss);
    reduce_kernel<<<1, 256, 0, stream>>>(row_loss, out);
}

// Round 2
// 128.726 us; speedup vs baseline: 1.2992x; 1.2992x over previous
//
#include <hip/hip_runtime.h>
#include <hip/hip_bf16.h>

#define S_DIM 2048
#define G_DIM 8
#define D_DIM 128
#define N_ROWS (S_DIM * G_DIM)   // 16384
#define SCALE 30.0f
#define NSPLIT 8
#define TCHUNK (S_DIM / NSPLIT)  // 256

typedef __attribute__((ext_vector_type(8))) short bf16x8;
typedef __attribute__((ext_vector_type(4))) float f32x4;

__device__ __forceinline__ float wave_allreduce_sum(float v) {
    #pragma unroll
    for (int m = 32; m >= 1; m >>= 1) v += __shfl_xor(v, m, 64);
    return v;
}

// ---------------------------------------------------------------------------
// Kernel A: normalize rows, centroids, exclusive-centroid cosine (all fp32),
// emit bf16 xn and bf16 cent_n for the MFMA stage.
// One block per speaker s; 8 waves = 8 utterances; lane handles dims l, l+64.
// ---------------------------------------------------------------------------
__global__ __launch_bounds__(512) void prep_kernel(
    const float* __restrict__ x,          // [S][G][D]
    __hip_bfloat16* __restrict__ xnb,     // [S*G][D]
    __hip_bfloat16* __restrict__ centb,   // [S][D]
    float* __restrict__ cosexc)           // [S*G]
{
    __shared__ float xs[G_DIM][D_DIM];
    __shared__ float csum[D_DIM];

    const int s    = blockIdx.x;
    const int g    = threadIdx.x >> 6;
    const int lane = threadIdx.x & 63;
    const int d0 = lane, d1 = lane + 64;

    const float* xr = x + (s * G_DIM + g) * D_DIM;
    float a0 = xr[d0], a1 = xr[d1];

    // row L2 normalize (clip 1e-12)
    float ss  = wave_allreduce_sum(a0 * a0 + a1 * a1);
    float inv = 1.0f / fmaxf(sqrtf(ss), 1e-12f);
    float x0 = a0 * inv, x1 = a1 * inv;

    xs[g][d0] = x0;
    xs[g][d1] = x1;
    __hip_bfloat16* xw = xnb + (s * G_DIM + g) * D_DIM;
    xw[d0] = __float2bfloat16(x0);
    xw[d1] = __float2bfloat16(x1);
    __syncthreads();

    // column sums over g
    if (threadIdx.x < D_DIM) {
        float c = 0.0f;
        #pragma unroll
        for (int gg = 0; gg < G_DIM; ++gg) c += xs[gg][threadIdx.x];
        csum[threadIdx.x] = c;
    }
    __syncthreads();

    // exclusive centroid: (sum - xn)/(G-1), normalize (clip 1e-8), cosine w/ xn
    float e0 = (csum[d0] - x0) * (1.0f / (G_DIM - 1));
    float e1 = (csum[d1] - x1) * (1.0f / (G_DIM - 1));
    float ess = wave_allreduce_sum(e0 * e0 + e1 * e1);
    float ed  = fmaxf(sqrtf(ess), 1e-8f);
    float dot = wave_allreduce_sum(x0 * e0 + x1 * e1);
    if (lane == 0) cosexc[s * G_DIM + g] = dot / ed;

    // centroid: cent = csum/8, cent_n = cent / clip(||cent||, 1e-8)
    if (g == 0) {
        float c0 = csum[d0], c1 = csum[d1];
        float css  = wave_allreduce_sum(c0 * c0 + c1 * c1);
        float cnrm = sqrtf(css) * (1.0f / G_DIM);          // ||cent||
        float scl  = (1.0f / G_DIM) / fmaxf(cnrm, 1e-8f);
        centb[s * D_DIM + d0] = __float2bfloat16(c0 * scl);
        centb[s * D_DIM + d1] = __float2bfloat16(c1 * scl);
    }
}

// ---------------------------------------------------------------------------
// Kernel B: scores via MFMA bf16 (fp32 acc) fused with softmax-denominator.
// t-dimension split NSPLIT ways across blockIdx.y for occupancy (was 1
// wave/SIMD -> latency-bound at 91us). Each block: 64 rows x 256 t.
// A-frag layout (16x16x32): A[m=lane&15][k=(lane>>4)*8 + j], j=0..7
// C/D layout: col(n) = lane&15, row(m) = (lane>>4)*4 + reg   [m89-verified]
// logsumexp uses fixed offset 30 (all logits in (0,30]): no max pass needed.
// ---------------------------------------------------------------------------
__global__ __launch_bounds__(256, 8) void score_kernel(
    const __hip_bfloat16* __restrict__ xnb,    // [N_ROWS][D]
    const __hip_bfloat16* __restrict__ centb,  // [S][D]
    const float* __restrict__ cosexc,          // [N_ROWS]
    float* __restrict__ psum,                  // [NSPLIT][N_ROWS] partial sum-exp
    float* __restrict__ plab)                  // [NSPLIT][N_ROWS] partial label logit
{
    const int wave  = threadIdx.x >> 6;
    const int lane  = threadIdx.x & 63;
    const int row0  = blockIdx.x * 64 + wave * 16;
    const int split = blockIdx.y;
    const int tbase = split * TCHUNK;
    const int nIdx  = lane & 15;   // A row-within-tile AND C col(t) index
    const int quad  = lane >> 4;

    // A fragments resident: 16 rows x 128 k
    const short* xsrc = (const short*)xnb;
    bf16x8 afrag[4];
    const int abase = (row0 + nIdx) * D_DIM + quad * 8;
    #pragma unroll
    for (int kc = 0; kc < 4; ++kc)
        afrag[kc] = *(const bf16x8*)(xsrc + abase + kc * 32);

    float sumexp[4] = {0.0f, 0.0f, 0.0f, 0.0f};
    float llab[4]   = {0.0f, 0.0f, 0.0f, 0.0f};

    const short* csrc = (const short*)centb;
    for (int t0 = tbase; t0 < tbase + TCHUNK; t0 += 16) {
        f32x4 acc = {0.0f, 0.0f, 0.0f, 0.0f};
        const int bbase = (t0 + nIdx) * D_DIM + quad * 8;
        #pragma unroll
        for (int kc = 0; kc < 4; ++kc) {
            bf16x8 bfrag = *(const bf16x8*)(csrc + bbase + kc * 32);
            acc = __builtin_amdgcn_mfma_f32_16x16x32_bf16(afrag[kc], bfrag, acc, 0, 0, 0);
        }
        const int t = t0 + nIdx;
        #pragma unroll
        for (int r = 0; r < 4; ++r) {
            const int grow = row0 + quad * 4 + r;
            float l = fmaxf(SCALE * acc[r], 1e-6f);
            if (t == (grow >> 3)) {              // diagonal: own-speaker entry
                l = fmaxf(SCALE * cosexc[grow], 1e-6f);
                llab[r] = l;                      // label logit (exact fp32)
            }
            sumexp[r] += __expf(l - SCALE);
        }
    }

    // reduce across the 16 lanes sharing a quad (they cover t mod 16)
    #pragma unroll
    for (int r = 0; r < 4; ++r) {
        #pragma unroll
        for (int msk = 1; msk <= 8; msk <<= 1) {
            sumexp[r] += __shfl_xor(sumexp[r], msk, 64);
            llab[r]   += __shfl_xor(llab[r], msk, 64);
        }
    }
    if (nIdx == 0) {
        #pragma unroll
        for (int r = 0; r < 4; ++r) {
            const int grow = row0 + quad * 4 + r;
            psum[split * N_ROWS + grow] = sumexp[r];
            plab[split * N_ROWS + grow] = llab[r];
        }
    }
}

// ---------------------------------------------------------------------------
// Kernel C: combine partials -> per-row loss -> mean (atomic accumulate).
// 64 blocks x 256 threads, 1 row/thread. d_out must be zeroed beforehand.
// ---------------------------------------------------------------------------
__global__ __launch_bounds__(256) void combine_kernel(
    const float* __restrict__ psum, const float* __restrict__ plab,
    float* __restrict__ out)
{
    __shared__ float red[4];
    const int row = blockIdx.x * 256 + threadIdx.x;

    float s = 0.0f, lab = 0.0f;
    #pragma unroll
    for (int j = 0; j < NSPLIT; ++j) {
        s   += psum[j * N_ROWS + row];
        lab += plab[j * N_ROWS + row];
    }
    float loss = SCALE + logf(s) - lab;   // -logp[row, label]

    float v = wave_allreduce_sum(loss);
    const int wave = threadIdx.x >> 6;
    if ((threadIdx.x & 63) == 0) red[wave] = v;
    __syncthreads();
    if (threadIdx.x == 0)
        atomicAdd(out, (red[0] + red[1] + red[2] + red[3]) * (1.0f / N_ROWS));
}

extern "C" void kernel_launch(void* const* d_in, const int* in_sizes, int n_in,
                              void* d_out, int out_size, void* d_ws, size_t ws_size,
                              hipStream_t stream) {
    const float* x = (const float*)d_in[0];
    char* ws = (char*)d_ws;

    size_t off = 0;
    __hip_bfloat16* xnb   = (__hip_bfloat16*)(ws + off); off += (size_t)N_ROWS * D_DIM * 2;  // 4 MB
    __hip_bfloat16* centb = (__hip_bfloat16*)(ws + off); off += (size_t)S_DIM * D_DIM * 2;   // 0.5 MB
    float* cosexc = (float*)(ws + off); off += (size_t)N_ROWS * 4;                            // 64 KB
    float* psum   = (float*)(ws + off); off += (size_t)NSPLIT * N_ROWS * 4;                   // 512 KB
    float* plab   = (float*)(ws + off); off += (size_t)NSPLIT * N_ROWS * 4;                   // 512 KB
    float* out = (float*)d_out;

    hipMemsetAsync(out, 0, sizeof(float), stream);
    prep_kernel<<<S_DIM, 512, 0, stream>>>(x, xnb, centb, cosexc);
    score_kernel<<<dim3(N_ROWS / 64, NSPLIT), 256, 0, stream>>>(xnb, centb, cosexc, psum, plab);
    combine_kernel<<<N_ROWS / 256, 256, 0, stream>>>(psum, plab, out);
}

// Round 3
// 91.961 us; speedup vs baseline: 1.8186x; 1.3998x over previous
//
#include <hip/hip_runtime.h>
#include <hip/hip_bf16.h>

#define S_DIM 2048
#define G_DIM 8
#define D_DIM 128
#define N_ROWS (S_DIM * G_DIM)   // 16384
#define SCALE 30.0f
#define NSPLIT 16
#define TCHUNK (S_DIM / NSPLIT)  // 128 -> 8 t-tiles of 16 per wave

typedef __attribute__((ext_vector_type(8))) short bf16x8;
typedef __attribute__((ext_vector_type(4))) float f32x4;

__device__ __forceinline__ float wave_allreduce_sum(float v) {
    #pragma unroll
    for (int m = 32; m >= 1; m >>= 1) v += __shfl_xor(v, m, 64);
    return v;
}

// ---------------------------------------------------------------------------
// Kernel A: normalize rows, centroids, exclusive-centroid cosine (all fp32),
// emit bf16 xn and bf16 cent_n for the MFMA stage.
// One block per speaker s; 8 waves = 8 utterances; lane handles dims l, l+64.
// ---------------------------------------------------------------------------
__global__ __launch_bounds__(512) void prep_kernel(
    const float* __restrict__ x,          // [S][G][D]
    __hip_bfloat16* __restrict__ xnb,     // [S*G][D]
    __hip_bfloat16* __restrict__ centb,   // [S][D]
    float* __restrict__ cosexc)           // [S*G]
{
    __shared__ float xs[G_DIM][D_DIM];
    __shared__ float csum[D_DIM];

    const int s    = blockIdx.x;
    const int g    = threadIdx.x >> 6;
    const int lane = threadIdx.x & 63;
    const int d0 = lane, d1 = lane + 64;

    const float* xr = x + (s * G_DIM + g) * D_DIM;
    float a0 = xr[d0], a1 = xr[d1];

    // row L2 normalize (clip 1e-12)
    float ss  = wave_allreduce_sum(a0 * a0 + a1 * a1);
    float inv = 1.0f / fmaxf(sqrtf(ss), 1e-12f);
    float x0 = a0 * inv, x1 = a1 * inv;

    xs[g][d0] = x0;
    xs[g][d1] = x1;
    __hip_bfloat16* xw = xnb + (s * G_DIM + g) * D_DIM;
    xw[d0] = __float2bfloat16(x0);
    xw[d1] = __float2bfloat16(x1);
    __syncthreads();

    // column sums over g
    if (threadIdx.x < D_DIM) {
        float c = 0.0f;
        #pragma unroll
        for (int gg = 0; gg < G_DIM; ++gg) c += xs[gg][threadIdx.x];
        csum[threadIdx.x] = c;
    }
    __syncthreads();

    // exclusive centroid: (sum - xn)/(G-1), normalize (clip 1e-8), cosine w/ xn
    float e0 = (csum[d0] - x0) * (1.0f / (G_DIM - 1));
    float e1 = (csum[d1] - x1) * (1.0f / (G_DIM - 1));
    float ess = wave_allreduce_sum(e0 * e0 + e1 * e1);
    float ed  = fmaxf(sqrtf(ess), 1e-8f);
    float dot = wave_allreduce_sum(x0 * e0 + x1 * e1);
    if (lane == 0) cosexc[s * G_DIM + g] = dot / ed;

    // centroid: cent = csum/8, cent_n = cent / clip(||cent||, 1e-8)
    if (g == 0) {
        float c0 = csum[d0], c1 = csum[d1];
        float css  = wave_allreduce_sum(c0 * c0 + c1 * c1);
        float cnrm = sqrtf(css) * (1.0f / G_DIM);          // ||cent||
        float scl  = (1.0f / G_DIM) / fmaxf(cnrm, 1e-8f);
        centb[s * D_DIM + d0] = __float2bfloat16(c0 * scl);
        centb[s * D_DIM + d1] = __float2bfloat16(c1 * scl);
    }
}

// ---------------------------------------------------------------------------
// Kernel B: fused scores + softmax-denominator.
// R1 post-mortem: 79% occupancy but all pipes idle -> per-wave latency-bound
// (1 MFMA per 16B B-load, chained). Fix: 4 A-tiles/wave (64 rows resident,
// 64 VGPRs) -> per t-tile 4 B-loads feed 16 MFMAs in 4 independent chains.
// B traffic 512MB -> 128MB. Grid 64 x NSPLIT=16 = 1024 blocks = 4/CU,
// 4 waves/SIMD at <=128 VGPR.
// A-frag (16x16x32): A[m=lane&15][k=(lane>>4)*8+j]. C/D: col=lane&15,
// row=(lane>>4)*4+reg [m89-verified].
// Diagonal band (8 speakers/wave) hits exactly one 16-t tile -> wave-uniform
// branch; plab[N_ROWS] written once by the owning split (no llab regs).
// logsumexp offset fixed at 30 (logits in (0,30]): no max pass.
// ---------------------------------------------------------------------------
__global__ __launch_bounds__(256, 4) void score_kernel(
    const __hip_bfloat16* __restrict__ xnb,    // [N_ROWS][D]
    const __hip_bfloat16* __restrict__ centb,  // [S][D]
    const float* __restrict__ cosexc,          // [N_ROWS]
    float* __restrict__ psum,                  // [NSPLIT][N_ROWS] partial sum-exp
    float* __restrict__ plab)                  // [N_ROWS] label logit (single owner)
{
    const int wave  = threadIdx.x >> 6;
    const int lane  = threadIdx.x & 63;
    const int row0  = (blockIdx.x * 4 + wave) * 64;   // 64 rows per wave
    const int split = blockIdx.y;
    const int tbase = split * TCHUNK;
    const int nIdx  = lane & 15;
    const int quad  = lane >> 4;
    const int s0    = row0 >> 3;                      // first speaker of this wave

    // A fragments resident: 4 tiles x 16 rows x 128 k
    const short* xsrc = (const short*)xnb;
    bf16x8 afrag[4][4];
    #pragma unroll
    for (int m = 0; m < 4; ++m) {
        const int abase = (row0 + m * 16 + nIdx) * D_DIM + quad * 8;
        #pragma unroll
        for (int kc = 0; kc < 4; ++kc)
            afrag[m][kc] = *(const bf16x8*)(xsrc + abase + kc * 32);
    }

    float sumexp[4][4];
    #pragma unroll
    for (int m = 0; m < 4; ++m)
        #pragma unroll
        for (int r = 0; r < 4; ++r) sumexp[m][r] = 0.0f;

    const short* csrc = (const short*)centb;
    for (int t0 = tbase; t0 < tbase + TCHUNK; t0 += 16) {
        // B loads first (4 independent dwordx4)
        bf16x8 bfrag[4];
        const int bbase = (t0 + nIdx) * D_DIM + quad * 8;
        #pragma unroll
        for (int kc = 0; kc < 4; ++kc)
            bfrag[kc] = *(const bf16x8*)(csrc + bbase + kc * 32);

        f32x4 acc[4];
        #pragma unroll
        for (int m = 0; m < 4; ++m) acc[m] = (f32x4){0.f, 0.f, 0.f, 0.f};
        #pragma unroll
        for (int kc = 0; kc < 4; ++kc)
            #pragma unroll
            for (int m = 0; m < 4; ++m)
                acc[m] = __builtin_amdgcn_mfma_f32_16x16x32_bf16(
                    afrag[m][kc], bfrag[kc], acc[m], 0, 0, 0);

        const int t = t0 + nIdx;
        if (t0 <= s0 + 7 && t0 + 16 > s0) {
            // rare tile containing this wave's diagonal band (wave-uniform test)
            #pragma unroll
            for (int m = 0; m < 4; ++m) {
                #pragma unroll
                for (int r = 0; r < 4; ++r) {
                    const int grow = row0 + m * 16 + quad * 4 + r;
                    float l = fmaxf(SCALE * acc[m][r], 1e-6f);
                    if (t == (grow >> 3)) {
                        l = fmaxf(SCALE * cosexc[grow], 1e-6f);
                        plab[grow] = l;           // exactly one writer per row
                    }
                    sumexp[m][r] += __expf(l - SCALE);
                }
            }
        } else {
            #pragma unroll
            for (int m = 0; m < 4; ++m) {
                #pragma unroll
                for (int r = 0; r < 4; ++r) {
                    float l = fmaxf(SCALE * acc[m][r], 1e-6f);
                    sumexp[m][r] += __expf(l - SCALE);
                }
            }
        }
    }

    // reduce across the 16 lanes sharing a quad (they cover t mod 16)
    #pragma unroll
    for (int m = 0; m < 4; ++m) {
        #pragma unroll
        for (int r = 0; r < 4; ++r) {
            #pragma unroll
            for (int msk = 1; msk <= 8; msk <<= 1)
                sumexp[m][r] += __shfl_xor(sumexp[m][r], msk, 64);
        }
    }
    if (nIdx == 0) {
        #pragma unroll
        for (int m = 0; m < 4; ++m)
            #pragma unroll
            for (int r = 0; r < 4; ++r)
                psum[split * N_ROWS + row0 + m * 16 + quad * 4 + r] = sumexp[m][r];
    }
}

// ---------------------------------------------------------------------------
// Kernel C: combine partials -> per-row loss -> mean (atomic accumulate).
// 64 blocks x 256 threads, 1 row/thread. d_out zeroed beforehand.
// ---------------------------------------------------------------------------
__global__ __launch_bounds__(256) void combine_kernel(
    const float* __restrict__ psum, const float* __restrict__ plab,
    float* __restrict__ out)
{
    __shared__ float red[4];
    const int row = blockIdx.x * 256 + threadIdx.x;

    float s = 0.0f;
    #pragma unroll
    for (int j = 0; j < NSPLIT; ++j) s += psum[j * N_ROWS + row];
    float loss = SCALE + logf(s) - plab[row];   // -logp[row, label]

    float v = wave_allreduce_sum(loss);
    const int wave = threadIdx.x >> 6;
    if ((threadIdx.x & 63) == 0) red[wave] = v;
    __syncthreads();
    if (threadIdx.x == 0)
        atomicAdd(out, (red[0] + red[1] + red[2] + red[3]) * (1.0f / N_ROWS));
}

extern "C" void kernel_launch(void* const* d_in, const int* in_sizes, int n_in,
                              void* d_out, int out_size, void* d_ws, size_t ws_size,
                              hipStream_t stream) {
    const float* x = (const float*)d_in[0];
    char* ws = (char*)d_ws;

    size_t off = 0;
    __hip_bfloat16* xnb   = (__hip_bfloat16*)(ws + off); off += (size_t)N_ROWS * D_DIM * 2;  // 4 MB
    __hip_bfloat16* centb = (__hip_bfloat16*)(ws + off); off += (size_t)S_DIM * D_DIM * 2;   // 0.5 MB
    float* cosexc = (float*)(ws + off); off += (size_t)N_ROWS * 4;                            // 64 KB
    float* psum   = (float*)(ws + off); off += (size_t)NSPLIT * N_ROWS * 4;                   // 1 MB
    float* plab   = (float*)(ws + off); off += (size_t)N_ROWS * 4;                            // 64 KB
    float* out = (float*)d_out;

    hipMemsetAsync(out, 0, sizeof(float), stream);
    prep_kernel<<<S_DIM, 512, 0, stream>>>(x, xnb, centb, cosexc);
    score_kernel<<<dim3(N_ROWS / 256, NSPLIT), 256, 0, stream>>>(xnb, centb, cosexc, psum, plab);
    combine_kernel<<<N_ROWS / 256, 256, 0, stream>>>(psum, plab, out);
}